// Round 3
// baseline (581.886 us; speedup 1.0000x reference)
//
#include <hip/hip_runtime.h>

#define B_SZ 1024
#define T_SZ 128
#define HID 512
#define LAB 100

// ---- d_ws layout (byte offsets) ----
#define OFF_X     0u          // int[262144]          1 MB
#define OFF_WH    1048576u    // ushort[262144]       512 KB
#define OFF_LEN   1572864u    // ushort[96000]
#define OFF_IPD   1764864u    // ushort[16384]
#define OFF_FC2   1797632u    // ushort[51200]
#define OFF_X2H   1900032u    // ushort[65536]        128 KB
#define OFF_FC2B  2031104u    // float[100] (+pad)
#define OFF_XIN   2097152u    // ushort[128][64][16][512] = 128 MB
#define WS_NEED   136314880u

typedef __attribute__((ext_vector_type(8))) short short8;
typedef __attribute__((ext_vector_type(4))) float float4v;
typedef __attribute__((ext_vector_type(4))) unsigned short us4;
typedef __attribute__((ext_vector_type(8))) __bf16 bf8_t;
typedef unsigned long long ull;

__device__ __attribute__((aligned(16))) unsigned char g_blob[WS_NEED]; // fallback only

__device__ __forceinline__ float bf2f(unsigned short u) {
    union { unsigned int i; float f; } z; z.i = ((unsigned int)u) << 16; return z.f;
}
__device__ __forceinline__ unsigned short f2bf(float f) {
    union { float f; unsigned int i; } z; z.f = f;
    unsigned int r = z.i + 0x7FFFu + ((z.i >> 16) & 1u);
    return (unsigned short)(r >> 16);
}
__device__ __forceinline__ float4v mfma16(short8 a, short8 b, float4v c) {
    return __builtin_amdgcn_mfma_f32_16x16x32_bf16(
        __builtin_bit_cast(bf8_t, a), __builtin_bit_cast(bf8_t, b), c, 0, 0, 0);
}

__global__ void conv_x_kernel(const int* __restrict__ xi, int* __restrict__ xo) {
    __shared__ int is64;
    if (threadIdx.x == 0) {
        int nz = 0;
        for (int j = 1; j < 64; j += 2) nz |= xi[j];
        is64 = (nz == 0) ? 1 : 0;
    }
    __syncthreads();
    const int n = B_SZ * T_SZ * 2;
    const int i64 = is64;
    for (int i = blockIdx.x * blockDim.x + threadIdx.x; i < n; i += gridDim.x * blockDim.x) {
        int v = i64 ? xi[2 * i] : xi[i];
        v = v < 0 ? 0 : (v > 255 ? 255 : v);
        xo[i] = v;
    }
}

__global__ void conv_floats_kernel(const float* __restrict__ len_e, const float* __restrict__ ipd_e,
                                   const float* __restrict__ h2h, const float* __restrict__ fc2,
                                   const float* __restrict__ x2h, const float* __restrict__ fc2b,
                                   unsigned short* __restrict__ o_len, unsigned short* __restrict__ o_ipd,
                                   unsigned short* __restrict__ o_wh, unsigned short* __restrict__ o_fc2,
                                   unsigned short* __restrict__ o_x2h, float* __restrict__ o_fc2b) {
    const int N0 = 96000, N1 = 16384, N2 = 262144, N3 = 51200, N4 = 65536, N5 = 100;
    const int total = N0 + N1 + N2 + N3 + N4 + N5;
    for (int i = blockIdx.x * blockDim.x + threadIdx.x; i < total; i += gridDim.x * blockDim.x) {
        int j = i;
        if (j < N0) { o_len[j] = f2bf(len_e[j]); continue; }
        j -= N0;
        if (j < N1) { o_ipd[j] = f2bf(ipd_e[j]); continue; }
        j -= N1;
        if (j < N2) { o_wh[j] = f2bf(h2h[j]); continue; }
        j -= N2;
        if (j < N3) { o_fc2[j] = f2bf(fc2[j]); continue; }
        j -= N3;
        if (j < N4) { o_x2h[j] = f2bf(x2h[j]); continue; }
        j -= N4;
        o_fc2b[j] = fc2b[j];
    }
}

// ---------------------------------------------------------------------------
// xin_kernel: xin[t][g][m][n] = (feats @ fc1^T + fc1_b) @ x2h^T + x2h_b + h2h_b
// 1024 blocks (t x 8 b-groups of 128 rows) x 256 threads. (unchanged, proven)
// ---------------------------------------------------------------------------
__launch_bounds__(256)
__global__ void xin_kernel(const int* __restrict__ w_x,
                           const unsigned short* __restrict__ w_len,
                           const unsigned short* __restrict__ w_ipd,
                           const float* __restrict__ fc1w, const float* __restrict__ fc1b,
                           const unsigned short* __restrict__ w_x2h,
                           const float* __restrict__ x2hb, const float* __restrict__ h2hb,
                           unsigned short* __restrict__ w_xin) {
    extern __shared__ unsigned short sm[];
    unsigned short* fT   = sm;
    unsigned short* fc1L = sm + 128 * 136;
    unsigned short* rT   = sm + 2 * 128 * 136;

    const int tid  = threadIdx.x;
    const int wv   = tid >> 6;
    const int ln   = tid & 63;
    const int mcol = ln & 15;
    const int q    = ln >> 4;
    const int t    = blockIdx.x >> 3;
    const int bg   = blockIdx.x & 7;

    {
        int row = tid >> 1, c = tid & 1;
        int idx = w_x[(bg * 128 + row) * 256 + t * 2 + c];
        const uint4* s4 = (const uint4*)((c ? w_ipd : w_len) + idx * 64);
        uint4* dst = (uint4*)&fT[row * 136 + c * 64];
#pragma unroll
        for (int i = 0; i < 8; i++) dst[i] = s4[i];
    }
#pragma unroll
    for (int it = 0; it < 8; it++) {
        int chunk = it * 256 + tid;
        int r = chunk >> 4, c8 = chunk & 15;
        const float* s = fc1w + r * 128 + c8 * 8;
        us4 a = { f2bf(s[0]), f2bf(s[1]), f2bf(s[2]), f2bf(s[3]) };
        us4 b = { f2bf(s[4]), f2bf(s[5]), f2bf(s[6]), f2bf(s[7]) };
        *(us4*)&fc1L[r * 136 + c8 * 8]     = a;
        *(us4*)&fc1L[r * 136 + c8 * 8 + 4] = b;
    }
    __syncthreads();

    for (int mt = 0; mt < 8; mt++) {
        float4v acc[2] = {{0.f,0.f,0.f,0.f},{0.f,0.f,0.f,0.f}};
#pragma unroll
        for (int kt = 0; kt < 4; kt++) {
            short8 bf = *(const short8*)&fT[(mt * 16 + mcol) * 136 + kt * 32 + q * 8];
#pragma unroll
            for (int u = 0; u < 2; u++) {
                int ntp = wv + u * 4;
                short8 fa = *(const short8*)&fc1L[(ntp * 16 + mcol) * 136 + kt * 32 + q * 8];
                acc[u] = mfma16(fa, bf, acc[u]);
            }
        }
#pragma unroll
        for (int u = 0; u < 2; u++) {
            int ntp = wv + u * 4;
            unsigned short o[4];
#pragma unroll
            for (int r = 0; r < 4; r++)
                o[r] = f2bf(acc[u][r] + fc1b[ntp * 16 + q * 4 + r]);
            us4 v = { o[0], o[1], o[2], o[3] };
            *(us4*)&rT[(mt * 16 + mcol) * 136 + ntp * 16 + q * 4] = v;
        }
    }
    __syncthreads();

    float bias[8][4];
#pragma unroll
    for (int i = 0; i < 8; i++)
#pragma unroll
        for (int r = 0; r < 4; r++) {
            int n = (wv * 8 + i) * 16 + q * 4 + r;
            bias[i][r] = x2hb[n] + h2hb[n];
        }
    for (int mt = 0; mt < 8; mt++) {
        float4v acc[8];
#pragma unroll
        for (int i = 0; i < 8; i++) acc[i] = (float4v){0.f,0.f,0.f,0.f};
#pragma unroll
        for (int kt = 0; kt < 4; kt++) {
            short8 bf = *(const short8*)&rT[(mt * 16 + mcol) * 136 + kt * 32 + q * 8];
#pragma unroll
            for (int i = 0; i < 8; i++) {
                int n16 = (wv * 8 + i) * 16;
                short8 fa = *(const short8*)(w_x2h + (n16 + mcol) * 128 + kt * 32 + q * 8);
                acc[i] = mfma16(fa, bf, acc[i]);
            }
        }
        int m = mt * 16 + mcol;
        int g = bg * 8 + (m >> 4), mm = m & 15;
#pragma unroll
        for (int i = 0; i < 8; i++) {
            int n0i = (wv * 8 + i) * 16 + q * 4;
            us4 v = { f2bf(acc[i][0] + bias[i][0]), f2bf(acc[i][1] + bias[i][1]),
                      f2bf(acc[i][2] + bias[i][2]), f2bf(acc[i][3] + bias[i][3]) };
            *(us4*)&w_xin[((t * 64 + g) * 16 + mm) * 512 + n0i] = v;
        }
    }
}

// ---------------------------------------------------------------------------
// RNN v4: 64 blocks x 256 threads = 4 waves (1/SIMD). Each wave owns 128
// hidden rows: whr[8][12] = 384 regs for Wh kt0..11 (1 wave/SIMD -> ~512-reg
// budget, r1's 320-cliff doesn't apply); kt12..15 in 128 KB LDS (swizzled).
// LDS read traffic/step: bh 4x16KB=64KB (was 128: h-broadcast redundancy
// halved) + sA 128KB = 192 KB (was 256). Half the barrier participants.
// MFMA/SIMD and VALU/SIMD unchanged. 8 independent acc streams give the
// single wave/SIMD enough ILP to pipeline ds_read->MFMA.
// Tripwire: WRITE_SIZE must stay ~400 KB (no spills).
// ---------------------------------------------------------------------------
__launch_bounds__(256, 1)
__global__ void rnn_kernel(const unsigned short* __restrict__ w_wh,
                           const unsigned short* __restrict__ w_xin,
                           const unsigned short* __restrict__ w_fc2,
                           const float* __restrict__ w_fc2b,
                           float* __restrict__ out) {
    extern __shared__ unsigned short sm2[];
    unsigned short* sA = sm2;            // Wh k 384..511: 65536 ushorts (128 KB)
    unsigned short* sH = sm2 + 65536;    // h dbuf: 2 x 8192 ushorts (32 KB)

    const int tid  = threadIdx.x;
    const int wv   = tid >> 6;           // 0..3
    const int ln   = tid & 63;
    const int mcol = ln & 15;            // batch col within block
    const int q    = ln >> 4;
    const int g    = blockIdx.x;
    const int b0   = g * 16;
    const int n0   = wv * 128;           // wave owns hidden rows n0..n0+127

    // ---- stage Wh kt 12..15 into LDS (swizzled) ----
    for (int it = 0; it < 32; it++) {
        int chunk = it * 256 + tid;          // 0..8191
        int r = chunk >> 4, c = chunk & 15;
        uint4 v = *(const uint4*)(w_wh + r * 512 + 384 + c * 8);
        *(uint4*)&sA[r * 128 + ((c ^ (r & 15)) & 15) * 8] = v;
    }
    // ---- zero h buffer 0 (8192 ushorts) ----
    {
        uint4 z = {0, 0, 0, 0};
#pragma unroll
        for (int it = 0; it < 4; it++)
            *(uint4*)&sH[(it * 256 + tid) * 8] = z;
    }
    // ---- Wh kt 0..11 into registers: 96 frags = 384 regs ----
    short8 whr[8][12];
#pragma unroll
    for (int nt = 0; nt < 8; nt++)
#pragma unroll
        for (int kt = 0; kt < 12; kt++)
            whr[nt][kt] = *(const short8*)(w_wh + (n0 + nt * 16 + mcol) * 512 + kt * 32 + q * 8);

    // ---- strength-reduced swizzle offsets (ushort units) ----
    // ((kt*4+q)^mcol)&63 = (kt>>2)*16 + ((kt&3)*4 ^ (mcol&12)) + (q ^ (mcol&3))
    const int qlo = (q ^ (mcol & 3)) * 8;
    int ej[4];
#pragma unroll
    for (int j = 0; j < 4; j++)
        ej[j] = ((j * 4) ^ (mcol & 12)) * 8;
    const int base_b = mcol * 512 + qlo;          // h-read base
    const int fbase  = (n0 + mcol) * 128 + qlo;   // sA-read base
    int hw_off[8];
#pragma unroll
    for (int nt = 0; nt < 8; nt++) {
        int n = n0 + nt * 16 + q * 4;
        hw_off[nt] = mcol * 512 + (((n >> 3) ^ mcol) & 63) * 8 + (n & 7);
    }

    // ---- xin prefetch (t=0); running pointer, stride = 64*16*512 ushorts ----
    const unsigned short* xin_p = w_xin + (g * 16 + mcol) * 512 + n0 + q * 4;
    us4 xq[8];
#pragma unroll
    for (int nt = 0; nt < 8; nt++)
        xq[nt] = *(const us4*)(xin_p + nt * 16);

    __syncthreads();

    for (int t = 0; t < T_SZ; t++) {
        const unsigned short* hRd = sH + ((t & 1) << 13);
        unsigned short* hWr = sH + (((t + 1) & 1) << 13);

        // ---- acc init from prefetched xin ----
        float4v acc[8];
#pragma unroll
        for (int nt = 0; nt < 8; nt++) {
            acc[nt][0] = bf2f(xq[nt][0]); acc[nt][1] = bf2f(xq[nt][1]);
            acc[nt][2] = bf2f(xq[nt][2]); acc[nt][3] = bf2f(xq[nt][3]);
        }
        // ---- prefetch xin(t+1) (hidden under MFMA phase) ----
        xin_p += 64 * 16 * 512;
        if (t + 1 < T_SZ) {
#pragma unroll
            for (int nt = 0; nt < 8; nt++)
                xq[nt] = *(const us4*)(xin_p + nt * 16);
        }

        // ---- Wh MFMAs: kt 0..11 from regs (1 bh ds_read + 8 MFMA each) ----
#pragma unroll
        for (int kt = 0; kt < 12; kt++) {
            short8 bh = *(const short8*)&hRd[base_b + ej[kt & 3] + (kt >> 2) * 128];
#pragma unroll
            for (int nt = 0; nt < 8; nt++)
                acc[nt] = mfma16(whr[nt][kt], bh, acc[nt]);
        }
        // ---- kt 12..15 from LDS ----
#pragma unroll
        for (int j = 0; j < 4; j++) {
            short8 bh = *(const short8*)&hRd[base_b + ej[j] + 384];
#pragma unroll
            for (int nt = 0; nt < 8; nt++) {
                short8 fa = *(const short8*)&sA[fbase + nt * 2048 + ej[j]];
                acc[nt] = mfma16(fa, bh, acc[nt]);
            }
        }

        // ---- fast tanh -> bf16, write h(t+1) into other buffer ----
#pragma unroll
        for (int nt = 0; nt < 8; nt++) {
            unsigned short o[4];
#pragma unroll
            for (int r = 0; r < 4; r++) {
                // tanh(v) = 1 - 2/(e^{2v}+1); exp inf/0 saturates to +-1,
                // so no clamp. Approx rcp ~1 ulp << bf16 quantization.
                float e  = __expf(2.0f * acc[nt][r]);
                float th = 1.0f - 2.0f * __builtin_amdgcn_rcpf(e + 1.0f);
                o[r] = f2bf(th);
            }
            us4 v4 = { o[0], o[1], o[2], o[3] };
            *(us4*)&hWr[hw_off[nt]] = v4;
        }
        __syncthreads();   // h(t+1) visible to all waves before next step
    }

    // final h is in buffer 0 (T_SZ even)
    unsigned short* hF = sH;

    // ---- fc2 epilogue: 7 label-tiles of 16 cover 112 >= 100 labels;
    //      4 waves take 2 tiles each (tile 7 skipped) ----
#pragma unroll
    for (int li = 0; li < 2; li++) {
        int lt = wv + 4 * li;            // 0..7
        if (lt >= 7) continue;
        int lA = lt * 16 + mcol; if (lA > 99) lA = 99;
        float4v a2 = {0.f, 0.f, 0.f, 0.f};
#pragma unroll
        for (int kt = 0; kt < 16; kt++) {
            short8 fa = *(const short8*)(w_fc2 + lA * 512 + kt * 32 + q * 8);
            short8 bh = *(const short8*)&hF[base_b + ej[kt & 3] + (kt >> 2) * 128];
            a2 = mfma16(fa, bh, a2);
        }
#pragma unroll
        for (int r = 0; r < 4; r++) {
            int l = lt * 16 + q * 4 + r;
            if (l < 100) out[(b0 + mcol) * 100 + l] = a2[r] + w_fc2b[l];
        }
    }
}

extern "C" void kernel_launch(void* const* d_in, const int* in_sizes, int n_in,
                              void* d_out, int out_size, void* d_ws, size_t ws_size,
                              hipStream_t stream) {
    unsigned char* base = (unsigned char*)d_ws;
    if (ws_size < (size_t)WS_NEED) {
        void* p = nullptr;
        hipGetSymbolAddress(&p, HIP_SYMBOL(g_blob));
        base = (unsigned char*)p;
    }
    int*            w_x    = (int*)(base + OFF_X);
    unsigned short* w_wh   = (unsigned short*)(base + OFF_WH);
    unsigned short* w_len  = (unsigned short*)(base + OFF_LEN);
    unsigned short* w_ipd  = (unsigned short*)(base + OFF_IPD);
    unsigned short* w_fc2  = (unsigned short*)(base + OFF_FC2);
    unsigned short* w_x2h  = (unsigned short*)(base + OFF_X2H);
    float*          w_fc2b = (float*)(base + OFF_FC2B);
    unsigned short* w_xin  = (unsigned short*)(base + OFF_XIN);

    static bool attr_set = false;
    if (!attr_set) {
        hipFuncSetAttribute((const void*)xin_kernel,
                            hipFuncAttributeMaxDynamicSharedMemorySize, 3 * 128 * 136 * 2);
        hipFuncSetAttribute((const void*)rnn_kernel,
                            hipFuncAttributeMaxDynamicSharedMemorySize, 163840);
        attr_set = true;
    }

    conv_x_kernel<<<256, 256, 0, stream>>>((const int*)d_in[0], w_x);
    conv_floats_kernel<<<1024, 256, 0, stream>>>(
        (const float*)d_in[1], (const float*)d_in[2], (const float*)d_in[7],
        (const float*)d_in[9], (const float*)d_in[5], (const float*)d_in[10],
        w_len, w_ipd, w_wh, w_fc2, w_x2h, w_fc2b);
    xin_kernel<<<1024, 256, 3 * 128 * 136 * 2, stream>>>(
        w_x, w_len, w_ipd,
        (const float*)d_in[3], (const float*)d_in[4],
        w_x2h, (const float*)d_in[6], (const float*)d_in[8],
        w_xin);
    rnn_kernel<<<64, 256, 163840, stream>>>(
        w_wh, w_xin, w_fc2, w_fc2b, (float*)d_out);
}

// Round 5
// 504.003 us; speedup vs baseline: 1.1545x; 1.1545x over previous
//
#include <hip/hip_runtime.h>

#define B_SZ 1024
#define T_SZ 128
#define HID 512
#define LAB 100

// ---- d_ws layout (byte offsets) ----
#define OFF_X     0u          // int[262144]          1 MB
#define OFF_WH    1048576u    // ushort[262144]       512 KB
#define OFF_LEN   1572864u    // ushort[96000]
#define OFF_IPD   1764864u    // ushort[16384]
#define OFF_FC2   1797632u    // ushort[51200]
#define OFF_X2H   1900032u    // ushort[65536]        128 KB
#define OFF_FC2B  2031104u    // float[100] (+pad)
#define OFF_FC1   2031616u    // ushort[16384]        32 KB (fc1 bf16)
#define OFF_XIN   2097152u    // ushort[128][64][16][512] = 128 MB
#define WS_NEED   136314880u

typedef __attribute__((ext_vector_type(8))) short short8;
typedef __attribute__((ext_vector_type(4))) float float4v;
typedef __attribute__((ext_vector_type(4))) unsigned short us4;
typedef __attribute__((ext_vector_type(8))) __bf16 bf8_t;
typedef unsigned long long ull;

__device__ __attribute__((aligned(16))) unsigned char g_blob[WS_NEED]; // fallback only

__device__ __forceinline__ float bf2f(unsigned short u) {
    union { unsigned int i; float f; } z; z.i = ((unsigned int)u) << 16; return z.f;
}
__device__ __forceinline__ unsigned short f2bf(float f) {
    union { float f; unsigned int i; } z; z.f = f;
    unsigned int r = z.i + 0x7FFFu + ((z.i >> 16) & 1u);
    return (unsigned short)(r >> 16);
}
__device__ __forceinline__ float4v mfma16(short8 a, short8 b, float4v c) {
    return __builtin_amdgcn_mfma_f32_16x16x32_bf16(
        __builtin_bit_cast(bf8_t, a), __builtin_bit_cast(bf8_t, b), c, 0, 0, 0);
}

__global__ void conv_x_kernel(const int* __restrict__ xi, int* __restrict__ xo) {
    __shared__ int is64;
    if (threadIdx.x == 0) {
        int nz = 0;
        for (int j = 1; j < 64; j += 2) nz |= xi[j];
        is64 = (nz == 0) ? 1 : 0;
    }
    __syncthreads();
    const int n = B_SZ * T_SZ * 2;
    const int i64 = is64;
    for (int i = blockIdx.x * blockDim.x + threadIdx.x; i < n; i += gridDim.x * blockDim.x) {
        int v = i64 ? xi[2 * i] : xi[i];
        v = v < 0 ? 0 : (v > 255 ? 255 : v);
        xo[i] = v;
    }
}

__global__ void conv_floats_kernel(const float* __restrict__ len_e, const float* __restrict__ ipd_e,
                                   const float* __restrict__ h2h, const float* __restrict__ fc2,
                                   const float* __restrict__ x2h, const float* __restrict__ fc2b,
                                   const float* __restrict__ fc1,
                                   unsigned short* __restrict__ o_len, unsigned short* __restrict__ o_ipd,
                                   unsigned short* __restrict__ o_wh, unsigned short* __restrict__ o_fc2,
                                   unsigned short* __restrict__ o_x2h, float* __restrict__ o_fc2b,
                                   unsigned short* __restrict__ o_fc1) {
    const int N0 = 96000, N1 = 16384, N2 = 262144, N3 = 51200, N4 = 65536, N5 = 100, N6 = 16384;
    const int total = N0 + N1 + N2 + N3 + N4 + N5 + N6;
    for (int i = blockIdx.x * blockDim.x + threadIdx.x; i < total; i += gridDim.x * blockDim.x) {
        int j = i;
        if (j < N0) { o_len[j] = f2bf(len_e[j]); continue; }
        j -= N0;
        if (j < N1) { o_ipd[j] = f2bf(ipd_e[j]); continue; }
        j -= N1;
        if (j < N2) { o_wh[j] = f2bf(h2h[j]); continue; }
        j -= N2;
        if (j < N3) { o_fc2[j] = f2bf(fc2[j]); continue; }
        j -= N3;
        if (j < N4) { o_x2h[j] = f2bf(x2h[j]); continue; }
        j -= N4;
        if (j < N5) { o_fc2b[j] = fc2b[j]; continue; }
        j -= N5;
        o_fc1[j] = f2bf(fc1[j]);
    }
}

// ---------------------------------------------------------------------------
// xin_kernel v2: 2048 blocks (128 t x 16 bgroups of 64 rows) x 256 threads.
// fc1 pre-converted to bf16 in workspace -> read fragments straight from L2
// (no fc1L staging). LDS = fT + rT = 34 KB -> 4 blocks/CU x 4 waves =
// 16 waves/CU (was 4). __launch_bounds__(256,4) caps VGPR for residency.
// ---------------------------------------------------------------------------
__launch_bounds__(256, 4)
__global__ void xin_kernel(const int* __restrict__ w_x,
                           const unsigned short* __restrict__ w_len,
                           const unsigned short* __restrict__ w_ipd,
                           const unsigned short* __restrict__ w_fc1,
                           const float* __restrict__ fc1b,
                           const unsigned short* __restrict__ w_x2h,
                           const float* __restrict__ x2hb, const float* __restrict__ h2hb,
                           unsigned short* __restrict__ w_xin) {
    extern __shared__ unsigned short sm[];
    unsigned short* fT = sm;              // 64 x 136 feats (bf16)
    unsigned short* rT = sm + 64 * 136;   // 64 x 136 fc1 output (bf16)

    const int tid  = threadIdx.x;
    const int wv   = tid >> 6;
    const int ln   = tid & 63;
    const int mcol = ln & 15;
    const int q    = ln >> 4;
    const int t    = blockIdx.x >> 4;
    const int bg   = blockIdx.x & 15;

    // ---- gather 64 rows of feats (len||ipd) into fT ----
    if (tid < 128) {
        int row = tid >> 1, c = tid & 1;
        int idx = w_x[(bg * 64 + row) * 256 + t * 2 + c];
        const uint4* s4 = (const uint4*)((c ? w_ipd : w_len) + idx * 64);
        uint4* dst = (uint4*)&fT[row * 136 + c * 64];
#pragma unroll
        for (int i = 0; i < 8; i++) dst[i] = s4[i];
    }
    __syncthreads();

    // ---- GEMM1: r = feats @ fc1^T + fc1_b  (64 rows x 128 n) ----
    for (int mt = 0; mt < 4; mt++) {
        float4v acc[2] = {{0.f,0.f,0.f,0.f},{0.f,0.f,0.f,0.f}};
#pragma unroll
        for (int kt = 0; kt < 4; kt++) {
            short8 bf = *(const short8*)&fT[(mt * 16 + mcol) * 136 + kt * 32 + q * 8];
#pragma unroll
            for (int u = 0; u < 2; u++) {
                int ntp = wv + u * 4;
                short8 fa = *(const short8*)(w_fc1 + (ntp * 16 + mcol) * 128 + kt * 32 + q * 8);
                acc[u] = mfma16(fa, bf, acc[u]);
            }
        }
#pragma unroll
        for (int u = 0; u < 2; u++) {
            int ntp = wv + u * 4;
            unsigned short o[4];
#pragma unroll
            for (int r = 0; r < 4; r++)
                o[r] = f2bf(acc[u][r] + fc1b[ntp * 16 + q * 4 + r]);
            us4 v = { o[0], o[1], o[2], o[3] };
            *(us4*)&rT[(mt * 16 + mcol) * 136 + ntp * 16 + q * 4] = v;
        }
    }
    __syncthreads();

    // ---- GEMM2: xin = r @ x2h^T + x2h_b + h2h_b  (64 rows x 512 n) ----
    float bias[8][4];
#pragma unroll
    for (int i = 0; i < 8; i++)
#pragma unroll
        for (int r = 0; r < 4; r++) {
            int n = (wv * 8 + i) * 16 + q * 4 + r;
            bias[i][r] = x2hb[n] + h2hb[n];
        }
    for (int mt = 0; mt < 4; mt++) {
        float4v acc[8];
#pragma unroll
        for (int i = 0; i < 8; i++) acc[i] = (float4v){0.f,0.f,0.f,0.f};
#pragma unroll
        for (int kt = 0; kt < 4; kt++) {
            short8 bf = *(const short8*)&rT[(mt * 16 + mcol) * 136 + kt * 32 + q * 8];
#pragma unroll
            for (int i = 0; i < 8; i++) {
                int n16 = (wv * 8 + i) * 16;
                short8 fa = *(const short8*)(w_x2h + (n16 + mcol) * 128 + kt * 32 + q * 8);
                acc[i] = mfma16(fa, bf, acc[i]);
            }
        }
        // batch index = bg*64 + mt*16 + mcol -> g = bg*4 + mt, mm = mcol
        int gidx = bg * 4 + mt;
#pragma unroll
        for (int i = 0; i < 8; i++) {
            int n0i = (wv * 8 + i) * 16 + q * 4;
            us4 v = { f2bf(acc[i][0] + bias[i][0]), f2bf(acc[i][1] + bias[i][1]),
                      f2bf(acc[i][2] + bias[i][2]), f2bf(acc[i][3] + bias[i][3]) };
            *(us4*)&w_xin[((t * 64 + gidx) * 16 + mcol) * 512 + n0i] = v;
        }
    }
}

// ---------------------------------------------------------------------------
// RNN v3 (verbatim round-2 kernel, 265 us proven): 64 blocks x 512 threads
// (8 waves, 2/SIMD). Wh kt0..11 in 192 VGPRs, kt12..15 in 128 KB LDS
// (swizzled); h double-buffered bf16 (2x16 KB) -> ONE barrier/step.
// Fast tanh + strength-reduced swizzle addressing + running xin pointer.
// Register budget at 2 waves/SIMD (320 unified cap): ~230 used, no spills.
// r3 lesson: 2 waves/SIMD is REQUIRED for latency hiding; do not drop to 1.
// ---------------------------------------------------------------------------
__launch_bounds__(512, 2)
__global__ void rnn_kernel(const unsigned short* __restrict__ w_wh,
                           const unsigned short* __restrict__ w_xin,
                           const unsigned short* __restrict__ w_fc2,
                           const float* __restrict__ w_fc2b,
                           float* __restrict__ out) {
    extern __shared__ unsigned short sm2[];
    unsigned short* sA = sm2;            // Wh k 384..511: 65536 ushorts (128 KB)
    unsigned short* sH = sm2 + 65536;    // h dbuf: 2 x 8192 ushorts (32 KB)

    const int tid  = threadIdx.x;
    const int wv   = tid >> 6;           // 0..7
    const int ln   = tid & 63;
    const int mcol = ln & 15;            // batch col within block
    const int q    = ln >> 4;
    const int g    = blockIdx.x;
    const int b0   = g * 16;
    const int n0   = wv * 64;            // wave owns hidden rows n0..n0+63

    // ---- stage Wh kt 12..15 into LDS (swizzled) ----
    for (int it = 0; it < 16; it++) {
        int chunk = it * 512 + tid;          // 0..8191
        int r = chunk >> 4, c = chunk & 15;
        uint4 v = *(const uint4*)(w_wh + r * 512 + 384 + c * 8);
        *(uint4*)&sA[r * 128 + ((c ^ (r & 15)) & 15) * 8] = v;
    }
    // ---- zero h buffer 0 ----
    {
        uint4 z = {0, 0, 0, 0};
        *(uint4*)&sH[tid * 8] = z;
        *(uint4*)&sH[(512 + tid) * 8] = z;
    }
    // ---- Wh kt 0..11 into registers: 48 frags = 192 VGPRs ----
    short8 whr[4][12];
#pragma unroll
    for (int nt = 0; nt < 4; nt++)
#pragma unroll
        for (int kt = 0; kt < 12; kt++)
            whr[nt][kt] = *(const short8*)(w_wh + (n0 + nt * 16 + mcol) * 512 + kt * 32 + q * 8);

    // ---- strength-reduced swizzle offsets (ushort units) ----
    // ((kt*4+q)^mcol)&63 = (kt>>2)*16 + ((kt&3)*4 ^ (mcol&12)) + (q ^ (mcol&3))
    const int qlo = (q ^ (mcol & 3)) * 8;
    int ej[4];
#pragma unroll
    for (int j = 0; j < 4; j++)
        ej[j] = ((j * 4) ^ (mcol & 12)) * 8;
    const int base_b = mcol * 512 + qlo;          // h-read base
    const int fbase  = (n0 + mcol) * 128 + qlo;   // sA-read base
    int hw_off[4];
#pragma unroll
    for (int nt = 0; nt < 4; nt++) {
        int n = n0 + nt * 16 + q * 4;
        hw_off[nt] = mcol * 512 + (((n >> 3) ^ mcol) & 63) * 8 + (n & 7);
    }

    // ---- xin prefetch (t=0); running pointer, stride = 64*16*512 ushorts ----
    const unsigned short* xin_p = w_xin + (g * 16 + mcol) * 512 + n0 + q * 4;
    us4 xq[4];
#pragma unroll
    for (int nt = 0; nt < 4; nt++)
        xq[nt] = *(const us4*)(xin_p + nt * 16);

    __syncthreads();

    for (int t = 0; t < T_SZ; t++) {
        const unsigned short* hRd = sH + ((t & 1) << 13);
        unsigned short* hWr = sH + (((t + 1) & 1) << 13);

        // ---- acc init from prefetched xin ----
        float4v acc[4];
#pragma unroll
        for (int nt = 0; nt < 4; nt++) {
            acc[nt][0] = bf2f(xq[nt][0]); acc[nt][1] = bf2f(xq[nt][1]);
            acc[nt][2] = bf2f(xq[nt][2]); acc[nt][3] = bf2f(xq[nt][3]);
        }
        // ---- prefetch xin(t+1) (hidden under MFMA phase) ----
        xin_p += 64 * 16 * 512;
        if (t + 1 < T_SZ) {
#pragma unroll
            for (int nt = 0; nt < 4; nt++)
                xq[nt] = *(const us4*)(xin_p + nt * 16);
        }

        // ---- Wh MFMAs: kt 0..11 from regs ----
#pragma unroll
        for (int kt = 0; kt < 12; kt++) {
            short8 bh = *(const short8*)&hRd[base_b + ej[kt & 3] + (kt >> 2) * 128];
#pragma unroll
            for (int nt = 0; nt < 4; nt++)
                acc[nt] = mfma16(whr[nt][kt], bh, acc[nt]);
        }
        // ---- kt 12..15 from LDS ----
#pragma unroll
        for (int j = 0; j < 4; j++) {
            short8 bh = *(const short8*)&hRd[base_b + ej[j] + 384];
#pragma unroll
            for (int nt = 0; nt < 4; nt++) {
                short8 fa = *(const short8*)&sA[fbase + nt * 2048 + ej[j]];
                acc[nt] = mfma16(fa, bh, acc[nt]);
            }
        }

        // ---- fast tanh -> bf16, write h(t+1) into other buffer ----
#pragma unroll
        for (int nt = 0; nt < 4; nt++) {
            unsigned short o[4];
#pragma unroll
            for (int r = 0; r < 4; r++) {
                // tanh(v) = 1 - 2/(e^{2v}+1); exp inf/0 saturates to +-1,
                // so no clamp. Approx rcp ~1 ulp << bf16 quantization.
                float e  = __expf(2.0f * acc[nt][r]);
                float th = 1.0f - 2.0f * __builtin_amdgcn_rcpf(e + 1.0f);
                o[r] = f2bf(th);
            }
            us4 v4 = { o[0], o[1], o[2], o[3] };
            *(us4*)&hWr[hw_off[nt]] = v4;
        }
        __syncthreads();   // h(t+1) visible to all waves before next step
    }

    // final h is in buffer 0 (T_SZ even)
    unsigned short* hF = sH;

    // ---- fc2 epilogue: waves 0..6 cover 112 >= 100 labels ----
    if (wv < 7) {
        int lA = wv * 16 + mcol; if (lA > 99) lA = 99;
        float4v a2 = {0.f, 0.f, 0.f, 0.f};
#pragma unroll
        for (int kt = 0; kt < 16; kt++) {
            short8 fa = *(const short8*)(w_fc2 + lA * 512 + kt * 32 + q * 8);
            short8 bh = *(const short8*)&hF[base_b + ej[kt & 3] + (kt >> 2) * 128];
            a2 = mfma16(fa, bh, a2);
        }
#pragma unroll
        for (int r = 0; r < 4; r++) {
            int l = wv * 16 + q * 4 + r;
            if (l < 100) out[(b0 + mcol) * 100 + l] = a2[r] + w_fc2b[l];
        }
    }
}

extern "C" void kernel_launch(void* const* d_in, const int* in_sizes, int n_in,
                              void* d_out, int out_size, void* d_ws, size_t ws_size,
                              hipStream_t stream) {
    unsigned char* base = (unsigned char*)d_ws;
    if (ws_size < (size_t)WS_NEED) {
        void* p = nullptr;
        hipGetSymbolAddress(&p, HIP_SYMBOL(g_blob));
        base = (unsigned char*)p;
    }
    int*            w_x    = (int*)(base + OFF_X);
    unsigned short* w_wh   = (unsigned short*)(base + OFF_WH);
    unsigned short* w_len  = (unsigned short*)(base + OFF_LEN);
    unsigned short* w_ipd  = (unsigned short*)(base + OFF_IPD);
    unsigned short* w_fc2  = (unsigned short*)(base + OFF_FC2);
    unsigned short* w_x2h  = (unsigned short*)(base + OFF_X2H);
    float*          w_fc2b = (float*)(base + OFF_FC2B);
    unsigned short* w_fc1  = (unsigned short*)(base + OFF_FC1);
    unsigned short* w_xin  = (unsigned short*)(base + OFF_XIN);

    static bool attr_set = false;
    if (!attr_set) {
        hipFuncSetAttribute((const void*)xin_kernel,
                            hipFuncAttributeMaxDynamicSharedMemorySize, 2 * 64 * 136 * 2);
        hipFuncSetAttribute((const void*)rnn_kernel,
                            hipFuncAttributeMaxDynamicSharedMemorySize, 163840);
        attr_set = true;
    }

    conv_x_kernel<<<256, 256, 0, stream>>>((const int*)d_in[0], w_x);
    conv_floats_kernel<<<1024, 256, 0, stream>>>(
        (const float*)d_in[1], (const float*)d_in[2], (const float*)d_in[7],
        (const float*)d_in[9], (const float*)d_in[5], (const float*)d_in[10],
        (const float*)d_in[3],
        w_len, w_ipd, w_wh, w_fc2, w_x2h, w_fc2b, w_fc1);
    xin_kernel<<<2048, 256, 2 * 64 * 136 * 2, stream>>>(
        w_x, w_len, w_ipd, w_fc1,
        (const float*)d_in[4],
        w_x2h, (const float*)d_in[6], (const float*)d_in[8],
        w_xin);
    rnn_kernel<<<64, 512, 163840, stream>>>(
        w_wh, w_xin, w_fc2, w_fc2b, (float*)d_out);
}

// Round 6
// 405.326 us; speedup vs baseline: 1.4356x; 1.2435x over previous
//
#include <hip/hip_runtime.h>

#define B_SZ 1024
#define T_SZ 128
#define HID 512
#define LAB 100

// ---- d_ws layout (byte offsets) ----
#define OFF_X     0u          // int[262144]          1 MB
#define OFF_WH    1048576u    // ushort[262144]       512 KB
#define OFF_LEN   1572864u    // ushort[96000]
#define OFF_IPD   1764864u    // ushort[16384]
#define OFF_FC2   1797632u    // ushort[51200]
#define OFF_X2H   1900032u    // ushort[65536]        128 KB
#define OFF_FC2B  2031104u    // float[100] (+pad)
#define OFF_CNT   2031616u    // uint[16] producer/consumer flags
#define OFF_XIN   2097152u    // ushort[128][64][16][512] = 128 MB
#define WS_NEED   136314880u

typedef __attribute__((ext_vector_type(8))) short short8;
typedef __attribute__((ext_vector_type(4))) float float4v;
typedef __attribute__((ext_vector_type(4))) unsigned short us4;
typedef __attribute__((ext_vector_type(8))) __bf16 bf8_t;
typedef unsigned long long ull;

__device__ __attribute__((aligned(16))) unsigned char g_blob[WS_NEED]; // fallback only

__device__ __forceinline__ float bf2f(unsigned short u) {
    union { unsigned int i; float f; } z; z.i = ((unsigned int)u) << 16; return z.f;
}
__device__ __forceinline__ unsigned short f2bf(float f) {
    union { float f; unsigned int i; } z; z.f = f;
    unsigned int r = z.i + 0x7FFFu + ((z.i >> 16) & 1u);
    return (unsigned short)(r >> 16);
}
__device__ __forceinline__ float4v mfma16(short8 a, short8 b, float4v c) {
    return __builtin_amdgcn_mfma_f32_16x16x32_bf16(
        __builtin_bit_cast(bf8_t, a), __builtin_bit_cast(bf8_t, b), c, 0, 0, 0);
}

__global__ void conv_x_kernel(const int* __restrict__ xi, int* __restrict__ xo,
                              unsigned int* __restrict__ cnt) {
    if (blockIdx.x == 0 && threadIdx.x < 16) cnt[threadIdx.x] = 0u;  // reset flags
    __shared__ int is64;
    if (threadIdx.x == 0) {
        int nz = 0;
        for (int j = 1; j < 64; j += 2) nz |= xi[j];
        is64 = (nz == 0) ? 1 : 0;
    }
    __syncthreads();
    const int n = B_SZ * T_SZ * 2;
    const int i64 = is64;
    for (int i = blockIdx.x * blockDim.x + threadIdx.x; i < n; i += gridDim.x * blockDim.x) {
        int v = i64 ? xi[2 * i] : xi[i];
        v = v < 0 ? 0 : (v > 255 ? 255 : v);
        xo[i] = v;
    }
}

__global__ void conv_floats_kernel(const float* __restrict__ len_e, const float* __restrict__ ipd_e,
                                   const float* __restrict__ h2h, const float* __restrict__ fc2,
                                   const float* __restrict__ x2h, const float* __restrict__ fc2b,
                                   unsigned short* __restrict__ o_len, unsigned short* __restrict__ o_ipd,
                                   unsigned short* __restrict__ o_wh, unsigned short* __restrict__ o_fc2,
                                   unsigned short* __restrict__ o_x2h, float* __restrict__ o_fc2b) {
    const int N0 = 96000, N1 = 16384, N2 = 262144, N3 = 51200, N4 = 65536, N5 = 100;
    const int total = N0 + N1 + N2 + N3 + N4 + N5;
    for (int i = blockIdx.x * blockDim.x + threadIdx.x; i < total; i += gridDim.x * blockDim.x) {
        int j = i;
        if (j < N0) { o_len[j] = f2bf(len_e[j]); continue; }
        j -= N0;
        if (j < N1) { o_ipd[j] = f2bf(ipd_e[j]); continue; }
        j -= N1;
        if (j < N2) { o_wh[j] = f2bf(h2h[j]); continue; }
        j -= N2;
        if (j < N3) { o_fc2[j] = f2bf(fc2[j]); continue; }
        j -= N3;
        if (j < N4) { o_x2h[j] = f2bf(x2h[j]); continue; }
        j -= N4;
        o_fc2b[j] = fc2b[j];
    }
}

// ---------------------------------------------------------------------------
// FUSED producer/consumer kernel, 1088 blocks x 512 threads, 160 KB dyn LDS.
//   blocks 0..63   : RNN consumer (proven v3 code, 265 us standalone).
//                    Occupies <=64 CUs; spins (s_sleep) on cnt[] once per
//                    8-step group before prefetching that group's xin.
//   blocks 64..1087: XIN producer (verbatim v1 xin, tid<256 active), t-major
//                    so early blocks produce early t. After stores:
//                    __threadfence (L2 writeback) + system-scope release add.
// Deadlock-free under ANY dispatch order: producers have no dependencies and
// consumers cap at 64 CUs of 256. Worst case degenerates to serial (=r2 perf).
// Cross-XCD visibility (G16): producer wbl2 via threadfence before flag;
// consumer relaxed system-scope spin then acquire threadfence (L1/L2 inv)
// before reading the group's xin data.
// ---------------------------------------------------------------------------
__launch_bounds__(512, 2)
__global__ void fused_kernel(const int* __restrict__ w_x,
                             const unsigned short* __restrict__ w_len,
                             const unsigned short* __restrict__ w_ipd,
                             const float* __restrict__ fc1w, const float* __restrict__ fc1b,
                             const unsigned short* __restrict__ w_x2h,
                             const float* __restrict__ x2hb, const float* __restrict__ h2hb,
                             unsigned short* __restrict__ w_xin,
                             const unsigned short* __restrict__ w_wh,
                             const unsigned short* __restrict__ w_fc2,
                             const float* __restrict__ w_fc2b,
                             float* __restrict__ out,
                             unsigned int* __restrict__ cnt) {
    extern __shared__ unsigned short sm[];
    const int tid  = threadIdx.x;
    const int wv   = tid >> 6;
    const int ln   = tid & 63;
    const int mcol = ln & 15;
    const int q    = ln >> 4;

    if (blockIdx.x >= 64) {
        // ================= XIN producer role (v1 code, tid<256) =============
        const int xbid = blockIdx.x - 64;
        const int t  = xbid >> 3;
        const int bg = xbid & 7;
        unsigned short* fT   = sm;
        unsigned short* fc1L = sm + 128 * 136;
        unsigned short* rT   = sm + 2 * 128 * 136;

        if (tid < 256) {
            {
                int row = tid >> 1, c = tid & 1;
                int idx = w_x[(bg * 128 + row) * 256 + t * 2 + c];
                const uint4* s4 = (const uint4*)((c ? w_ipd : w_len) + idx * 64);
                uint4* dst = (uint4*)&fT[row * 136 + c * 64];
#pragma unroll
                for (int i = 0; i < 8; i++) dst[i] = s4[i];
            }
#pragma unroll
            for (int it = 0; it < 8; it++) {
                int chunk = it * 256 + tid;
                int r = chunk >> 4, c8 = chunk & 15;
                const float* s = fc1w + r * 128 + c8 * 8;
                us4 a = { f2bf(s[0]), f2bf(s[1]), f2bf(s[2]), f2bf(s[3]) };
                us4 b = { f2bf(s[4]), f2bf(s[5]), f2bf(s[6]), f2bf(s[7]) };
                *(us4*)&fc1L[r * 136 + c8 * 8]     = a;
                *(us4*)&fc1L[r * 136 + c8 * 8 + 4] = b;
            }
        }
        __syncthreads();

        if (tid < 256) {
            for (int mt = 0; mt < 8; mt++) {
                float4v acc[2] = {{0.f,0.f,0.f,0.f},{0.f,0.f,0.f,0.f}};
#pragma unroll
                for (int kt = 0; kt < 4; kt++) {
                    short8 bf = *(const short8*)&fT[(mt * 16 + mcol) * 136 + kt * 32 + q * 8];
#pragma unroll
                    for (int u = 0; u < 2; u++) {
                        int ntp = wv + u * 4;
                        short8 fa = *(const short8*)&fc1L[(ntp * 16 + mcol) * 136 + kt * 32 + q * 8];
                        acc[u] = mfma16(fa, bf, acc[u]);
                    }
                }
#pragma unroll
                for (int u = 0; u < 2; u++) {
                    int ntp = wv + u * 4;
                    unsigned short o[4];
#pragma unroll
                    for (int r = 0; r < 4; r++)
                        o[r] = f2bf(acc[u][r] + fc1b[ntp * 16 + q * 4 + r]);
                    us4 v = { o[0], o[1], o[2], o[3] };
                    *(us4*)&rT[(mt * 16 + mcol) * 136 + ntp * 16 + q * 4] = v;
                }
            }
        }
        __syncthreads();

        if (tid < 256) {
            float bias[8][4];
#pragma unroll
            for (int i = 0; i < 8; i++)
#pragma unroll
                for (int r = 0; r < 4; r++) {
                    int n = (wv * 8 + i) * 16 + q * 4 + r;
                    bias[i][r] = x2hb[n] + h2hb[n];
                }
            for (int mt = 0; mt < 8; mt++) {
                float4v acc[8];
#pragma unroll
                for (int i = 0; i < 8; i++) acc[i] = (float4v){0.f,0.f,0.f,0.f};
#pragma unroll
                for (int kt = 0; kt < 4; kt++) {
                    short8 bf = *(const short8*)&rT[(mt * 16 + mcol) * 136 + kt * 32 + q * 8];
#pragma unroll
                    for (int i = 0; i < 8; i++) {
                        int n16 = (wv * 8 + i) * 16;
                        short8 fa = *(const short8*)(w_x2h + (n16 + mcol) * 128 + kt * 32 + q * 8);
                        acc[i] = mfma16(fa, bf, acc[i]);
                    }
                }
                int m = mt * 16 + mcol;
                int g = bg * 8 + (m >> 4), mm = m & 15;
#pragma unroll
                for (int i = 0; i < 8; i++) {
                    int n0i = (wv * 8 + i) * 16 + q * 4;
                    us4 v = { f2bf(acc[i][0] + bias[i][0]), f2bf(acc[i][1] + bias[i][1]),
                              f2bf(acc[i][2] + bias[i][2]), f2bf(acc[i][3] + bias[i][3]) };
                    *(us4*)&w_xin[((t * 64 + g) * 16 + mm) * 512 + n0i] = v;
                }
            }
        }
        __syncthreads();                     // all stores retired (vmcnt drain)
        if (tid == 0) {
            __threadfence();                 // write back L2 -> device visible
            __hip_atomic_fetch_add(&cnt[t >> 3], 1u,
                                   __ATOMIC_RELEASE, __HIP_MEMORY_SCOPE_SYSTEM);
        }
        return;
    }

    // ==================== RNN consumer role (v3 code) =======================
    unsigned short* sA = sm;            // Wh k 384..511: 65536 ushorts (128 KB)
    unsigned short* sH = sm + 65536;    // h dbuf: 2 x 8192 ushorts (32 KB)

    const int g    = blockIdx.x;
    const int b0   = g * 16;
    const int n0   = wv * 64;           // wave owns hidden rows n0..n0+63

    // ---- stage Wh kt 12..15 into LDS (swizzled) ----
    for (int it = 0; it < 16; it++) {
        int chunk = it * 512 + tid;          // 0..8191
        int r = chunk >> 4, c = chunk & 15;
        uint4 v = *(const uint4*)(w_wh + r * 512 + 384 + c * 8);
        *(uint4*)&sA[r * 128 + ((c ^ (r & 15)) & 15) * 8] = v;
    }
    // ---- zero h buffer 0 ----
    {
        uint4 z = {0, 0, 0, 0};
        *(uint4*)&sH[tid * 8] = z;
        *(uint4*)&sH[(512 + tid) * 8] = z;
    }
    // ---- Wh kt 0..11 into registers: 48 frags = 192 regs ----
    short8 whr[4][12];
#pragma unroll
    for (int nt = 0; nt < 4; nt++)
#pragma unroll
        for (int kt = 0; kt < 12; kt++)
            whr[nt][kt] = *(const short8*)(w_wh + (n0 + nt * 16 + mcol) * 512 + kt * 32 + q * 8);

    // ---- strength-reduced swizzle offsets (ushort units) ----
    const int qlo = (q ^ (mcol & 3)) * 8;
    int ej[4];
#pragma unroll
    for (int j = 0; j < 4; j++)
        ej[j] = ((j * 4) ^ (mcol & 12)) * 8;
    const int base_b = mcol * 512 + qlo;          // h-read base
    const int fbase  = (n0 + mcol) * 128 + qlo;   // sA-read base
    int hw_off[4];
#pragma unroll
    for (int nt = 0; nt < 4; nt++) {
        int n = n0 + nt * 16 + q * 4;
        hw_off[nt] = mcol * 512 + (((n >> 3) ^ mcol) & 63) * 8 + (n & 7);
    }

    // ---- wait for xin group 0 (t = 0..7) ----
    if (tid == 0) {
        while (__hip_atomic_load(&cnt[0], __ATOMIC_RELAXED, __HIP_MEMORY_SCOPE_SYSTEM) < 64u)
            __builtin_amdgcn_s_sleep(16);
        __threadfence();                 // acquire: invalidate L1/L2 for data reads
    }
    __syncthreads();                     // covers staging writes + group-0 ready

    // ---- xin prefetch (t=0); running pointer, stride = 64*16*512 ushorts ----
    const unsigned short* xin_p = w_xin + (g * 16 + mcol) * 512 + n0 + q * 4;
    us4 xq[4];
#pragma unroll
    for (int nt = 0; nt < 4; nt++)
        xq[nt] = *(const us4*)(xin_p + nt * 16);

    for (int t = 0; t < T_SZ; t++) {
        // ---- once per 8-step group: ensure next group's xin is ready ----
        if ((((t + 1) & 7) == 0) && (t + 1) < T_SZ) {
            if (tid == 0) {
                const int gp = (t + 1) >> 3;
                while (__hip_atomic_load(&cnt[gp], __ATOMIC_RELAXED, __HIP_MEMORY_SCOPE_SYSTEM) < 64u)
                    __builtin_amdgcn_s_sleep(16);
                __threadfence();
            }
            __syncthreads();
        }

        const unsigned short* hRd = sH + ((t & 1) << 13);
        unsigned short* hWr = sH + (((t + 1) & 1) << 13);

        // ---- acc init from prefetched xin ----
        float4v acc[4];
#pragma unroll
        for (int nt = 0; nt < 4; nt++) {
            acc[nt][0] = bf2f(xq[nt][0]); acc[nt][1] = bf2f(xq[nt][1]);
            acc[nt][2] = bf2f(xq[nt][2]); acc[nt][3] = bf2f(xq[nt][3]);
        }
        // ---- prefetch xin(t+1) (hidden under MFMA phase) ----
        xin_p += 64 * 16 * 512;
        if (t + 1 < T_SZ) {
#pragma unroll
            for (int nt = 0; nt < 4; nt++)
                xq[nt] = *(const us4*)(xin_p + nt * 16);
        }

        // ---- Wh MFMAs: kt 0..11 from regs ----
#pragma unroll
        for (int kt = 0; kt < 12; kt++) {
            short8 bh = *(const short8*)&hRd[base_b + ej[kt & 3] + (kt >> 2) * 128];
#pragma unroll
            for (int nt = 0; nt < 4; nt++)
                acc[nt] = mfma16(whr[nt][kt], bh, acc[nt]);
        }
        // ---- kt 12..15 from LDS ----
#pragma unroll
        for (int j = 0; j < 4; j++) {
            short8 bh = *(const short8*)&hRd[base_b + ej[j] + 384];
#pragma unroll
            for (int nt = 0; nt < 4; nt++) {
                short8 fa = *(const short8*)&sA[fbase + nt * 2048 + ej[j]];
                acc[nt] = mfma16(fa, bh, acc[nt]);
            }
        }

        // ---- fast tanh -> bf16, write h(t+1) into other buffer ----
#pragma unroll
        for (int nt = 0; nt < 4; nt++) {
            unsigned short o[4];
#pragma unroll
            for (int r = 0; r < 4; r++) {
                float e  = __expf(2.0f * acc[nt][r]);
                float th = 1.0f - 2.0f * __builtin_amdgcn_rcpf(e + 1.0f);
                o[r] = f2bf(th);
            }
            us4 v4 = { o[0], o[1], o[2], o[3] };
            *(us4*)&hWr[hw_off[nt]] = v4;
        }
        __syncthreads();   // h(t+1) visible to all waves before next step
    }

    // final h is in buffer 0 (T_SZ even)
    unsigned short* hF = sH;

    // ---- fc2 epilogue: waves 0..6 cover 112 >= 100 labels ----
    if (wv < 7) {
        int lA = wv * 16 + mcol; if (lA > 99) lA = 99;
        float4v a2 = {0.f, 0.f, 0.f, 0.f};
#pragma unroll
        for (int kt = 0; kt < 16; kt++) {
            short8 fa = *(const short8*)(w_fc2 + lA * 512 + kt * 32 + q * 8);
            short8 bh = *(const short8*)&hF[base_b + ej[kt & 3] + (kt >> 2) * 128];
            a2 = mfma16(fa, bh, a2);
        }
#pragma unroll
        for (int r = 0; r < 4; r++) {
            int l = wv * 16 + q * 4 + r;
            if (l < 100) out[(b0 + mcol) * 100 + l] = a2[r] + w_fc2b[l];
        }
    }
}

extern "C" void kernel_launch(void* const* d_in, const int* in_sizes, int n_in,
                              void* d_out, int out_size, void* d_ws, size_t ws_size,
                              hipStream_t stream) {
    unsigned char* base = (unsigned char*)d_ws;
    if (ws_size < (size_t)WS_NEED) {
        void* p = nullptr;
        hipGetSymbolAddress(&p, HIP_SYMBOL(g_blob));
        base = (unsigned char*)p;
    }
    int*            w_x    = (int*)(base + OFF_X);
    unsigned short* w_wh   = (unsigned short*)(base + OFF_WH);
    unsigned short* w_len  = (unsigned short*)(base + OFF_LEN);
    unsigned short* w_ipd  = (unsigned short*)(base + OFF_IPD);
    unsigned short* w_fc2  = (unsigned short*)(base + OFF_FC2);
    unsigned short* w_x2h  = (unsigned short*)(base + OFF_X2H);
    float*          w_fc2b = (float*)(base + OFF_FC2B);
    unsigned int*   w_cnt  = (unsigned int*)(base + OFF_CNT);
    unsigned short* w_xin  = (unsigned short*)(base + OFF_XIN);

    static bool attr_set = false;
    if (!attr_set) {
        hipFuncSetAttribute((const void*)fused_kernel,
                            hipFuncAttributeMaxDynamicSharedMemorySize, 163840);
        attr_set = true;
    }

    conv_x_kernel<<<256, 256, 0, stream>>>((const int*)d_in[0], w_x, w_cnt);
    conv_floats_kernel<<<1024, 256, 0, stream>>>(
        (const float*)d_in[1], (const float*)d_in[2], (const float*)d_in[7],
        (const float*)d_in[9], (const float*)d_in[5], (const float*)d_in[10],
        w_len, w_ipd, w_wh, w_fc2, w_x2h, w_fc2b);
    fused_kernel<<<1088, 512, 163840, stream>>>(
        w_x, w_len, w_ipd,
        (const float*)d_in[3], (const float*)d_in[4],
        w_x2h, (const float*)d_in[6], (const float*)d_in[8],
        w_xin,
        w_wh, w_fc2, w_fc2b, (float*)d_out, w_cnt);
}